// Round 7
// baseline (337.140 us; speedup 1.0000x reference)
//
#include <hip/hip_runtime.h>

#define N_NODES 40000
#define N_EDGES 640000
#define DIM 128
#define N_LAYERS 3

typedef __attribute__((ext_vector_type(8))) short bf16x8_t;
typedef __attribute__((ext_vector_type(4))) float f32x4_t;

__device__ __forceinline__ unsigned short f2bf(float x) {
    unsigned int u = __float_as_uint(x);
    return (unsigned short)((u + 0x7FFF + ((u >> 16) & 1)) >> 16);  // RNE
}
__device__ __forceinline__ float bf2f(unsigned short h) {
    return __uint_as_float(((unsigned int)h) << 16);
}

// ---------------- preprocessing: CSR by dst ----------------

__global__ void hist_kernel(const int* __restrict__ dst, int* __restrict__ deg) {
    int i = blockIdx.x * blockDim.x + threadIdx.x;
    if (i < N_EDGES) atomicAdd(&deg[dst[i]], 1);
}

__global__ void scan1_kernel(const int* __restrict__ deg, int* __restrict__ offsets,
                             float* __restrict__ inv_deg, int* __restrict__ bsum) {
    __shared__ int sd[256];
    int t = threadIdx.x, i = blockIdx.x * 256 + t;
    int v = (i < N_NODES) ? deg[i] : 0;
    if (i < N_NODES) inv_deg[i] = 1.0f / fmaxf((float)v, 1.0f);
    sd[t] = v;
    __syncthreads();
#pragma unroll
    for (int off = 1; off < 256; off <<= 1) {
        int x = (t >= off) ? sd[t - off] : 0;
        __syncthreads();
        sd[t] += x;
        __syncthreads();
    }
    if (i < N_NODES) offsets[i] = sd[t] - v;  // block-local exclusive
    if (t == 255) bsum[blockIdx.x] = sd[255];
}

__global__ void scan2_kernel(const int* __restrict__ bsum, int* __restrict__ boff) {
    __shared__ int sd[256];
    const int nb = (N_NODES + 255) / 256;
    int t = threadIdx.x;
    int v = (t < nb) ? bsum[t] : 0;
    sd[t] = v;
    __syncthreads();
#pragma unroll
    for (int off = 1; off < 256; off <<= 1) {
        int x = (t >= off) ? sd[t - off] : 0;
        __syncthreads();
        sd[t] += x;
        __syncthreads();
    }
    if (t < nb) boff[t] = sd[t] - v;
}

__global__ void scan3_kernel(int* __restrict__ offsets, const int* __restrict__ deg,
                             const int* __restrict__ boff) {
    int i = blockIdx.x * 256 + threadIdx.x;
    if (i < N_NODES) {
        int o = offsets[i] + boff[blockIdx.x];
        offsets[i] = o;
        if (i == N_NODES - 1) offsets[N_NODES] = o + deg[i];
    }
}

__global__ void scatter_kernel(const int* __restrict__ src, const int* __restrict__ dst,
                               const int* __restrict__ offsets, int* __restrict__ cursor,
                               int* __restrict__ csr_src) {
    int i = blockIdx.x * blockDim.x + threadIdx.x;
    if (i < N_EDGES) {
        int d = dst[i];
        int pos = atomicAdd(&cursor[d], 1);
        csr_src[offsets[d] + pos] = src[i];
    }
}

// ---------------- weight prep: W[k][n] fp32 -> Wt[n][k] bf16 hi/lo ----------------
__global__ void wprep_kernel(const float* __restrict__ w_self, const float* __restrict__ w_neigh,
                             unsigned short* __restrict__ wt_hi, unsigned short* __restrict__ wt_lo) {
    int i = blockIdx.x * blockDim.x + threadIdx.x;  // [ls][n][k]
    if (i >= N_LAYERS * 2 * DIM * DIM) return;
    int k = i & (DIM - 1);
    int n = (i >> 7) & (DIM - 1);
    int ls = i >> 14;
    int l = ls >> 1, s = ls & 1;
    const float* W = (s ? w_neigh : w_self) + (size_t)l * DIM * DIM;
    float v = W[k * DIM + n];
    unsigned short h = f2bf(v);
    wt_hi[i] = h;
    wt_lo[i] = f2bf(v - bf2f(h));
}

// ---------------- x -> bf16 hi/lo split ----------------
__global__ void split_kernel(const float* __restrict__ in, unsigned short* __restrict__ hi,
                             unsigned short* __restrict__ lo) {
    int i = blockIdx.x * blockDim.x + threadIdx.x;
    if (i >= N_NODES * DIM / 4) return;
    float4 v = ((const float4*)in)[i];
    ushort4 H, L;
    H.x = f2bf(v.x); L.x = f2bf(v.x - bf2f(H.x));
    H.y = f2bf(v.y); L.y = f2bf(v.y - bf2f(H.y));
    H.z = f2bf(v.z); L.z = f2bf(v.z - bf2f(H.z));
    H.w = f2bf(v.w); L.w = f2bf(v.w - bf2f(H.w));
    ((ushort4*)hi)[i] = H;
    ((ushort4*)lo)[i] = L;
}

// ---------------- kernel A: dual GEMM  P = h@Ws + b (fp32),  Q = h@Wn (bf16) ----------------
// Register-B, barrier-free: weights are 128x128, so each wave's B-frags for one
// (kh, source) slice are 8 bf16x8 loaded straight from global (L1/L2-hot: same
// addresses in every wave/block). No LDS, no __syncthreads — pure MFMA + VMEM.
// Block = 64 rows x 128 cols, wave = 32 rows x 64 cols. A-frags loaded once per
// kh and shared by both sources. Split-bf16 3-term per source (fp32-equivalent).
__global__ __launch_bounds__(256) void gemm_pq_kernel(
    const unsigned short* __restrict__ h_hi, const unsigned short* __restrict__ h_lo,
    const unsigned short* __restrict__ wt_hi, const unsigned short* __restrict__ wt_lo,
    const float* __restrict__ bias,
    float* __restrict__ P, unsigned short* __restrict__ Qb) {
    const int tid = threadIdx.x;
    const int wave = tid >> 6, lane = tid & 63;
    const int quad = lane >> 4, m = lane & 15;
    const int rowW = blockIdx.x * 64 + (wave >> 1) * 32;  // waves 0,1: rows 0-31; 2,3: rows 32-63
    const int colW = (wave & 1) * 64;                     // waves 0,2: cols 0-63; 1,3: cols 64-127

    f32x4_t accP[2][4], accQ[2][4];
#pragma unroll
    for (int rt = 0; rt < 2; ++rt)
#pragma unroll
        for (int jt = 0; jt < 4; ++jt) {
            accP[rt][jt] = {0.f, 0.f, 0.f, 0.f};
            accQ[rt][jt] = {0.f, 0.f, 0.f, 0.f};
        }

#pragma unroll
    for (int kh = 0; kh < 4; ++kh) {          // K = 128 in 32-chunks
        const int kg = kh * 32 + quad * 8;
        bf16x8_t ah[2], al[2];
#pragma unroll
        for (int rt = 0; rt < 2; ++rt) {
            size_t aoff = (size_t)(rowW + rt * 16 + m) * DIM + kg;
            ah[rt] = *(const bf16x8_t*)&h_hi[aoff];
            al[rt] = *(const bf16x8_t*)&h_lo[aoff];
        }
#pragma unroll
        for (int s = 0; s < 2; ++s) {          // s=0: Ws -> P, s=1: Wn -> Q
            const unsigned short* Whi = wt_hi + s * DIM * DIM;
            const unsigned short* Wlo = wt_lo + s * DIM * DIM;
            bf16x8_t Bh[4], Bl[4];
#pragma unroll
            for (int jt = 0; jt < 4; ++jt) {
                size_t boff = (size_t)(colW + jt * 16 + m) * DIM + kg;
                Bh[jt] = *(const bf16x8_t*)&Whi[boff];
                Bl[jt] = *(const bf16x8_t*)&Wlo[boff];
            }
#pragma unroll
            for (int rt = 0; rt < 2; ++rt)
#pragma unroll
                for (int jt = 0; jt < 4; ++jt) {
                    f32x4_t a = s ? accQ[rt][jt] : accP[rt][jt];
                    a = __builtin_amdgcn_mfma_f32_16x16x32_bf16(ah[rt], Bh[jt], a, 0, 0, 0);
                    a = __builtin_amdgcn_mfma_f32_16x16x32_bf16(ah[rt], Bl[jt], a, 0, 0, 0);
                    a = __builtin_amdgcn_mfma_f32_16x16x32_bf16(al[rt], Bh[jt], a, 0, 0, 0);
                    if (s) accQ[rt][jt] = a; else accP[rt][jt] = a;
                }
        }
    }

    // epilogue: C/D layout col=lane&15, row=quad*4+reg
#pragma unroll
    for (int rt = 0; rt < 2; ++rt)
#pragma unroll
        for (int jt = 0; jt < 4; ++jt) {
            int col = colW + jt * 16 + m;
            float bv = bias[col];
#pragma unroll
            for (int r4 = 0; r4 < 4; ++r4) {
                int row = rowW + rt * 16 + quad * 4 + r4;
                P[(size_t)row * DIM + col] = accP[rt][jt][r4] + bv;
                Qb[(size_t)row * DIM + col] = f2bf(accQ[rt][jt][r4]);
            }
        }
}

// ---------------- kernel B: mean-gather of Q + P + relu -> next h (or final out) ----------------
// One wave per node. 16 lanes per row chunk (16B bf16x8), 4 edge-groups,
// 4-deep row-load pipeline (16 edges in flight per wave iteration).
__global__ void agg_epi_kernel(const unsigned short* __restrict__ Qb,
                               const float* __restrict__ P,
                               const int* __restrict__ offsets, const int* __restrict__ csr_src,
                               const float* __restrict__ inv_deg,
                               unsigned short* __restrict__ hi_out, unsigned short* __restrict__ lo_out,
                               float* __restrict__ fout, int write_f32, int relu) {
    int node = (blockIdx.x * blockDim.x + threadIdx.x) >> 6;
    int lane = threadIdx.x & 63;
    if (node >= N_NODES) return;
    const int g = lane >> 4, c = lane & 15;
    int e0 = offsets[node], e1 = offsets[node + 1];
    float acc[8] = {0.f, 0.f, 0.f, 0.f, 0.f, 0.f, 0.f, 0.f};
    for (int base = e0; base < e1; base += 16) {
        int idx[4];
        float f[4];
#pragma unroll
        for (int i = 0; i < 4; ++i) {
            int e = base + i * 4 + g;
            bool v = e < e1;
            f[i] = v ? 1.f : 0.f;
            idx[i] = v ? csr_src[e] : 0;
        }
        bf16x8_t r[4];
#pragma unroll
        for (int i = 0; i < 4; ++i)
            r[i] = *(const bf16x8_t*)&Qb[(size_t)idx[i] * DIM + c * 8];
#pragma unroll
        for (int i = 0; i < 4; ++i)
#pragma unroll
            for (int j = 0; j < 8; ++j)
                acc[j] = fmaf(f[i], bf2f((unsigned short)r[i][j]), acc[j]);
    }
#pragma unroll
    for (int j = 0; j < 8; ++j) {
        acc[j] += __shfl_xor(acc[j], 16, 64);
        acc[j] += __shfl_xor(acc[j], 32, 64);
    }
    if (g == 0) {
        float w = inv_deg[node];
        float4 p0 = *(const float4*)&P[(size_t)node * DIM + c * 8];
        float4 p1 = *(const float4*)&P[(size_t)node * DIM + c * 8 + 4];
        float o[8];
        o[0] = p0.x + acc[0] * w; o[1] = p0.y + acc[1] * w;
        o[2] = p0.z + acc[2] * w; o[3] = p0.w + acc[3] * w;
        o[4] = p1.x + acc[4] * w; o[5] = p1.y + acc[5] * w;
        o[6] = p1.z + acc[6] * w; o[7] = p1.w + acc[7] * w;
        if (relu) {
#pragma unroll
            for (int j = 0; j < 8; ++j) o[j] = fmaxf(o[j], 0.f);
        }
        if (write_f32) {
            *(float4*)&fout[(size_t)node * DIM + c * 8] = make_float4(o[0], o[1], o[2], o[3]);
            *(float4*)&fout[(size_t)node * DIM + c * 8 + 4] = make_float4(o[4], o[5], o[6], o[7]);
        } else {
            bf16x8_t H, L;
#pragma unroll
            for (int j = 0; j < 8; ++j) {
                unsigned short hh = f2bf(o[j]);
                H[j] = (short)hh;
                L[j] = (short)f2bf(o[j] - bf2f(hh));
            }
            *(bf16x8_t*)&hi_out[(size_t)node * DIM + c * 8] = H;
            *(bf16x8_t*)&lo_out[(size_t)node * DIM + c * 8] = L;
        }
    }
}

// ---------------- launch ----------------

extern "C" void kernel_launch(void* const* d_in, const int* in_sizes, int n_in,
                              void* d_out, int out_size, void* d_ws, size_t ws_size,
                              hipStream_t stream) {
    const float* x      = (const float*)d_in[0];
    const int*   src    = (const int*)d_in[1];
    const int*   dst    = (const int*)d_in[2];
    const float* w_self = (const float*)d_in[3];
    const float* w_neigh= (const float*)d_in[4];
    const float* b      = (const float*)d_in[5];
    float* out = (float*)d_out;

    // workspace carve (~64 MB)
    char* ws = (char*)d_ws;
    unsigned short* h_hi = (unsigned short*)ws; ws += (size_t)N_NODES * DIM * 2;
    unsigned short* h_lo = (unsigned short*)ws; ws += (size_t)N_NODES * DIM * 2;
    float*          Pbuf = (float*)ws;          ws += (size_t)N_NODES * DIM * 4;
    unsigned short* Qbuf = (unsigned short*)ws; ws += (size_t)N_NODES * DIM * 2;
    unsigned short* wt_hi= (unsigned short*)ws; ws += (size_t)N_LAYERS * 2 * DIM * DIM * 2;
    unsigned short* wt_lo= (unsigned short*)ws; ws += (size_t)N_LAYERS * 2 * DIM * DIM * 2;
    int*   deg     = (int*)ws;  ws += (size_t)N_NODES * 4;
    int*   offsets = (int*)ws;  ws += (size_t)(N_NODES + 4) * 4;
    int*   cursor  = (int*)ws;  ws += (size_t)N_NODES * 4;
    int*   csr_src = (int*)ws;  ws += (size_t)N_EDGES * 4;
    float* inv_deg = (float*)ws; ws += (size_t)N_NODES * 4;
    int*   bsum    = (int*)ws;  ws += 256 * 4;
    int*   boff    = (int*)ws;

    const int NB = (N_NODES + 255) / 256;  // 157

    hipMemsetAsync(deg, 0, (size_t)(N_NODES + (N_NODES + 4) + N_NODES) * 4, stream);

    hist_kernel<<<(N_EDGES + 255) / 256, 256, 0, stream>>>(dst, deg);
    scan1_kernel<<<NB, 256, 0, stream>>>(deg, offsets, inv_deg, bsum);
    scan2_kernel<<<1, 256, 0, stream>>>(bsum, boff);
    scan3_kernel<<<NB, 256, 0, stream>>>(offsets, deg, boff);
    scatter_kernel<<<(N_EDGES + 255) / 256, 256, 0, stream>>>(src, dst, offsets, cursor, csr_src);
    wprep_kernel<<<(N_LAYERS * 2 * DIM * DIM + 255) / 256, 256, 0, stream>>>(w_self, w_neigh, wt_hi, wt_lo);
    split_kernel<<<(N_NODES * DIM / 4 + 255) / 256, 256, 0, stream>>>(x, h_hi, h_lo);

    const int GEMM_BLOCKS = N_NODES / 64;           // 625 (exact)
    const int AGG_BLOCKS = (N_NODES * 64) / 256;    // 10000 (exact)
    for (int l = 0; l < N_LAYERS; ++l) {
        int last = (l == N_LAYERS - 1);
        gemm_pq_kernel<<<GEMM_BLOCKS, 256, 0, stream>>>(
            h_hi, h_lo,
            wt_hi + (size_t)l * 2 * DIM * DIM, wt_lo + (size_t)l * 2 * DIM * DIM,
            b + (size_t)l * DIM, Pbuf, Qbuf);
        agg_epi_kernel<<<AGG_BLOCKS, 256, 0, stream>>>(
            Qbuf, Pbuf, offsets, csr_src, inv_deg,
            h_hi, h_lo, out, last ? 1 : 0, last ? 0 : 1);
    }
}

// Round 8
// 331.952 us; speedup vs baseline: 1.0156x; 1.0156x over previous
//
#include <hip/hip_runtime.h>

#define N_NODES 40000
#define N_EDGES 640000
#define DIM 128
#define N_LAYERS 3

typedef __attribute__((ext_vector_type(8))) short bf16x8_t;
typedef __attribute__((ext_vector_type(4))) float f32x4_t;

__device__ __forceinline__ unsigned short f2bf(float x) {
    unsigned int u = __float_as_uint(x);
    return (unsigned short)((u + 0x7FFF + ((u >> 16) & 1)) >> 16);  // RNE
}
__device__ __forceinline__ float bf2f(unsigned short h) {
    return __uint_as_float(((unsigned int)h) << 16);
}

// ---------------- preprocessing: CSR by dst ----------------

__global__ void hist_kernel(const int* __restrict__ dst, int* __restrict__ deg) {
    int i = blockIdx.x * blockDim.x + threadIdx.x;
    if (i < N_EDGES) atomicAdd(&deg[dst[i]], 1);
}

__global__ void scan1_kernel(const int* __restrict__ deg, int* __restrict__ offsets,
                             float* __restrict__ inv_deg, int* __restrict__ bsum) {
    __shared__ int sd[256];
    int t = threadIdx.x, i = blockIdx.x * 256 + t;
    int v = (i < N_NODES) ? deg[i] : 0;
    if (i < N_NODES) inv_deg[i] = 1.0f / fmaxf((float)v, 1.0f);
    sd[t] = v;
    __syncthreads();
#pragma unroll
    for (int off = 1; off < 256; off <<= 1) {
        int x = (t >= off) ? sd[t - off] : 0;
        __syncthreads();
        sd[t] += x;
        __syncthreads();
    }
    if (i < N_NODES) offsets[i] = sd[t] - v;  // block-local exclusive
    if (t == 255) bsum[blockIdx.x] = sd[255];
}

__global__ void scan2_kernel(const int* __restrict__ bsum, int* __restrict__ boff) {
    __shared__ int sd[256];
    const int nb = (N_NODES + 255) / 256;
    int t = threadIdx.x;
    int v = (t < nb) ? bsum[t] : 0;
    sd[t] = v;
    __syncthreads();
#pragma unroll
    for (int off = 1; off < 256; off <<= 1) {
        int x = (t >= off) ? sd[t - off] : 0;
        __syncthreads();
        sd[t] += x;
        __syncthreads();
    }
    if (t < nb) boff[t] = sd[t] - v;
}

__global__ void scan3_kernel(int* __restrict__ offsets, const int* __restrict__ deg,
                             const int* __restrict__ boff) {
    int i = blockIdx.x * 256 + threadIdx.x;
    if (i < N_NODES) {
        int o = offsets[i] + boff[blockIdx.x];
        offsets[i] = o;
        if (i == N_NODES - 1) offsets[N_NODES] = o + deg[i];
    }
}

__global__ void scatter_kernel(const int* __restrict__ src, const int* __restrict__ dst,
                               const int* __restrict__ offsets, int* __restrict__ cursor,
                               int* __restrict__ csr_src) {
    int i = blockIdx.x * blockDim.x + threadIdx.x;
    if (i < N_EDGES) {
        int d = dst[i];
        int pos = atomicAdd(&cursor[d], 1);
        csr_src[offsets[d] + pos] = src[i];
    }
}

// ---------------- weight prep: W[k][n] fp32 -> Wt[n][k] bf16 hi/lo ----------------
__global__ void wprep_kernel(const float* __restrict__ w_self, const float* __restrict__ w_neigh,
                             unsigned short* __restrict__ wt_hi, unsigned short* __restrict__ wt_lo) {
    int i = blockIdx.x * blockDim.x + threadIdx.x;  // [ls][n][k]
    if (i >= N_LAYERS * 2 * DIM * DIM) return;
    int k = i & (DIM - 1);
    int n = (i >> 7) & (DIM - 1);
    int ls = i >> 14;
    int l = ls >> 1, s = ls & 1;
    const float* W = (s ? w_neigh : w_self) + (size_t)l * DIM * DIM;
    float v = W[k * DIM + n];
    unsigned short h = f2bf(v);
    wt_hi[i] = h;
    wt_lo[i] = f2bf(v - bf2f(h));
}

// ---------------- x -> bf16 hi/lo split ----------------
__global__ void split_kernel(const float* __restrict__ in, unsigned short* __restrict__ hi,
                             unsigned short* __restrict__ lo) {
    int i = blockIdx.x * blockDim.x + threadIdx.x;
    if (i >= N_NODES * DIM / 4) return;
    float4 v = ((const float4*)in)[i];
    ushort4 H, L;
    H.x = f2bf(v.x); L.x = f2bf(v.x - bf2f(H.x));
    H.y = f2bf(v.y); L.y = f2bf(v.y - bf2f(H.y));
    H.z = f2bf(v.z); L.z = f2bf(v.z - bf2f(H.z));
    H.w = f2bf(v.w); L.w = f2bf(v.w - bf2f(H.w));
    ((ushort4*)hi)[i] = H;
    ((ushort4*)lo)[i] = L;
}

// ---------------- kernel A (layer 0 only): P0 = x@Ws + b (fp32), Q0 = x@Wn (bf16) ----------------
// Register-B, barrier-free (weights L1/L2-hot: same addresses every wave/block).
__global__ __launch_bounds__(256) void gemm_pq_kernel(
    const unsigned short* __restrict__ h_hi, const unsigned short* __restrict__ h_lo,
    const unsigned short* __restrict__ wt_hi, const unsigned short* __restrict__ wt_lo,
    const float* __restrict__ bias,
    float* __restrict__ P, unsigned short* __restrict__ Qb) {
    const int tid = threadIdx.x;
    const int wave = tid >> 6, lane = tid & 63;
    const int quad = lane >> 4, m = lane & 15;
    const int rowW = blockIdx.x * 64 + (wave >> 1) * 32;
    const int colW = (wave & 1) * 64;

    f32x4_t accP[2][4], accQ[2][4];
#pragma unroll
    for (int rt = 0; rt < 2; ++rt)
#pragma unroll
        for (int jt = 0; jt < 4; ++jt) {
            accP[rt][jt] = {0.f, 0.f, 0.f, 0.f};
            accQ[rt][jt] = {0.f, 0.f, 0.f, 0.f};
        }

#pragma unroll 1
    for (int kh = 0; kh < 4; ++kh) {
        const int kg = kh * 32 + quad * 8;
        bf16x8_t ah[2], al[2];
#pragma unroll
        for (int rt = 0; rt < 2; ++rt) {
            size_t aoff = (size_t)(rowW + rt * 16 + m) * DIM + kg;
            ah[rt] = *(const bf16x8_t*)&h_hi[aoff];
            al[rt] = *(const bf16x8_t*)&h_lo[aoff];
        }
#pragma unroll
        for (int s = 0; s < 2; ++s) {
            const unsigned short* Whi = wt_hi + s * DIM * DIM;
            const unsigned short* Wlo = wt_lo + s * DIM * DIM;
            bf16x8_t Bh[4], Bl[4];
#pragma unroll
            for (int jt = 0; jt < 4; ++jt) {
                size_t boff = (size_t)(colW + jt * 16 + m) * DIM + kg;
                Bh[jt] = *(const bf16x8_t*)&Whi[boff];
                Bl[jt] = *(const bf16x8_t*)&Wlo[boff];
            }
#pragma unroll
            for (int rt = 0; rt < 2; ++rt)
#pragma unroll
                for (int jt = 0; jt < 4; ++jt) {
                    f32x4_t a = s ? accQ[rt][jt] : accP[rt][jt];
                    a = __builtin_amdgcn_mfma_f32_16x16x32_bf16(ah[rt], Bh[jt], a, 0, 0, 0);
                    a = __builtin_amdgcn_mfma_f32_16x16x32_bf16(ah[rt], Bl[jt], a, 0, 0, 0);
                    a = __builtin_amdgcn_mfma_f32_16x16x32_bf16(al[rt], Bh[jt], a, 0, 0, 0);
                    if (s) accQ[rt][jt] = a; else accP[rt][jt] = a;
                }
        }
    }

#pragma unroll
    for (int rt = 0; rt < 2; ++rt)
#pragma unroll
        for (int jt = 0; jt < 4; ++jt) {
            int col = colW + jt * 16 + m;
            float bv = bias[col];
#pragma unroll
            for (int r4 = 0; r4 < 4; ++r4) {
                int row = rowW + rt * 16 + quad * 4 + r4;
                P[(size_t)row * DIM + col] = accP[rt][jt][r4] + bv;
                Qb[(size_t)row * DIM + col] = f2bf(accQ[rt][jt][r4]);
            }
        }
}

// ---------------- fused boundary kernel: h=relu(P+agg(Q)) in LDS, then dual GEMM ----------------
// Block = 64 dst nodes, 4 waves, 3 blocks/CU (LDS 35 KB, VGPR<=170).
// Phase 1: 16-lane groups gather Q rows (bf16, 2-deep pipeline), + own P row, relu,
//          split-bf16 h tile -> LDS. h never touches global memory.
// Phase 2: wave = 32 rows x 64 cols; A-frags from LDS, B-frags (hi/lo) from global
//          (L1-hot); 3-term split-bf16 MFMA -> P_out (fp32 + next bias), Q_out (bf16).
#define FPITCH 136  // 128 + 8 pad shorts: 2-way max bank aliasing (free)
__global__ __launch_bounds__(256, 3) void fused_layer_kernel(
    const unsigned short* __restrict__ Q_in, const float* __restrict__ P_in,
    const int* __restrict__ offsets, const int* __restrict__ csr_src,
    const float* __restrict__ inv_deg,
    const unsigned short* __restrict__ wt_hi, const unsigned short* __restrict__ wt_lo,
    const float* __restrict__ bias_next,
    float* __restrict__ P_out, unsigned short* __restrict__ Q_out) {
    __shared__ unsigned short sHhi[64][FPITCH];  // 17.4 KB
    __shared__ unsigned short sHlo[64][FPITCH];  // 17.4 KB

    const int tid = threadIdx.x;
    const int wave = tid >> 6, lane = tid & 63;
    const int quad = lane >> 4, m = lane & 15;
    const int node0 = blockIdx.x * 64;

    // ---- phase 1: gather + epilogue of layer l -> h tile in LDS ----
    {
        const int g = lane >> 4, c = lane & 15;  // node-group, 16B column chunk
#pragma unroll
        for (int i = 0; i < 4; ++i) {
            int nl = wave * 16 + i * 4 + g;      // local node 0..63
            int node = node0 + nl;
            int e0 = offsets[node], e1 = offsets[node + 1];
            float acc[8] = {0.f, 0.f, 0.f, 0.f, 0.f, 0.f, 0.f, 0.f};
            int e = e0;
            for (; e + 1 < e1; e += 2) {
                int sa = csr_src[e], sb = csr_src[e + 1];
                bf16x8_t va = *(const bf16x8_t*)&Q_in[(size_t)sa * DIM + c * 8];
                bf16x8_t vb = *(const bf16x8_t*)&Q_in[(size_t)sb * DIM + c * 8];
#pragma unroll
                for (int j = 0; j < 8; ++j)
                    acc[j] += bf2f((unsigned short)va[j]) + bf2f((unsigned short)vb[j]);
            }
            if (e < e1) {
                int sa = csr_src[e];
                bf16x8_t va = *(const bf16x8_t*)&Q_in[(size_t)sa * DIM + c * 8];
#pragma unroll
                for (int j = 0; j < 8; ++j) acc[j] += bf2f((unsigned short)va[j]);
            }
            float w = inv_deg[node];
            float4 p0 = *(const float4*)&P_in[(size_t)node * DIM + c * 8];
            float4 p1 = *(const float4*)&P_in[(size_t)node * DIM + c * 8 + 4];
            float o[8];
            o[0] = p0.x + acc[0] * w; o[1] = p0.y + acc[1] * w;
            o[2] = p0.z + acc[2] * w; o[3] = p0.w + acc[3] * w;
            o[4] = p1.x + acc[4] * w; o[5] = p1.y + acc[5] * w;
            o[6] = p1.z + acc[6] * w; o[7] = p1.w + acc[7] * w;
            bf16x8_t H, L;
#pragma unroll
            for (int j = 0; j < 8; ++j) {
                float v = fmaxf(o[j], 0.f);      // relu (always: this kernel is inter-layer)
                unsigned short hh = f2bf(v);
                H[j] = (short)hh;
                L[j] = (short)f2bf(v - bf2f(hh));
            }
            *(bf16x8_t*)&sHhi[nl][c * 8] = H;
            *(bf16x8_t*)&sHlo[nl][c * 8] = L;
        }
    }
    __syncthreads();

    // ---- phase 2: dual GEMM for layer l+1 ----
    const int rowL = (wave >> 1) * 32;   // local rows 0-31 / 32-63
    const int colW = (wave & 1) * 64;    // cols 0-63 / 64-127
    f32x4_t accP[2][4], accQ[2][4];
#pragma unroll
    for (int rt = 0; rt < 2; ++rt)
#pragma unroll
        for (int jt = 0; jt < 4; ++jt) {
            accP[rt][jt] = {0.f, 0.f, 0.f, 0.f};
            accQ[rt][jt] = {0.f, 0.f, 0.f, 0.f};
        }

#pragma unroll 1
    for (int kh = 0; kh < 4; ++kh) {
        const int kg = kh * 32 + quad * 8;
        bf16x8_t ah[2], al[2];
#pragma unroll
        for (int rt = 0; rt < 2; ++rt) {
            ah[rt] = *(const bf16x8_t*)&sHhi[rowL + rt * 16 + m][kg];
            al[rt] = *(const bf16x8_t*)&sHlo[rowL + rt * 16 + m][kg];
        }
#pragma unroll
        for (int s = 0; s < 2; ++s) {
            const unsigned short* Whi = wt_hi + s * DIM * DIM;
            const unsigned short* Wlo = wt_lo + s * DIM * DIM;
            bf16x8_t Bh[4], Bl[4];
#pragma unroll
            for (int jt = 0; jt < 4; ++jt) {
                size_t boff = (size_t)(colW + jt * 16 + m) * DIM + kg;
                Bh[jt] = *(const bf16x8_t*)&Whi[boff];
                Bl[jt] = *(const bf16x8_t*)&Wlo[boff];
            }
#pragma unroll
            for (int rt = 0; rt < 2; ++rt)
#pragma unroll
                for (int jt = 0; jt < 4; ++jt) {
                    f32x4_t a = s ? accQ[rt][jt] : accP[rt][jt];
                    a = __builtin_amdgcn_mfma_f32_16x16x32_bf16(ah[rt], Bh[jt], a, 0, 0, 0);
                    a = __builtin_amdgcn_mfma_f32_16x16x32_bf16(ah[rt], Bl[jt], a, 0, 0, 0);
                    a = __builtin_amdgcn_mfma_f32_16x16x32_bf16(al[rt], Bh[jt], a, 0, 0, 0);
                    if (s) accQ[rt][jt] = a; else accP[rt][jt] = a;
                }
        }
    }

    // epilogue: C/D layout col=lane&15, row=quad*4+reg
#pragma unroll
    for (int rt = 0; rt < 2; ++rt)
#pragma unroll
        for (int jt = 0; jt < 4; ++jt) {
            int col = colW + jt * 16 + m;
            float bv = bias_next[col];
#pragma unroll
            for (int r4 = 0; r4 < 4; ++r4) {
                int row = node0 + rowL + rt * 16 + quad * 4 + r4;
                P_out[(size_t)row * DIM + col] = accP[rt][jt][r4] + bv;
                Q_out[(size_t)row * DIM + col] = f2bf(accQ[rt][jt][r4]);
            }
        }
}

// ---------------- final kernel: out = P + mean-gather(Q), fp32, no relu ----------------
__global__ void final_agg_kernel(const unsigned short* __restrict__ Qb,
                                 const float* __restrict__ P,
                                 const int* __restrict__ offsets, const int* __restrict__ csr_src,
                                 const float* __restrict__ inv_deg,
                                 float* __restrict__ fout) {
    int node = (blockIdx.x * blockDim.x + threadIdx.x) >> 6;
    int lane = threadIdx.x & 63;
    if (node >= N_NODES) return;
    const int g = lane >> 4, c = lane & 15;
    int e0 = offsets[node], e1 = offsets[node + 1];
    float acc[8] = {0.f, 0.f, 0.f, 0.f, 0.f, 0.f, 0.f, 0.f};
    for (int base = e0; base < e1; base += 16) {
        int idx[4];
        float f[4];
#pragma unroll
        for (int i = 0; i < 4; ++i) {
            int e = base + i * 4 + g;
            bool v = e < e1;
            f[i] = v ? 1.f : 0.f;
            idx[i] = v ? csr_src[e] : 0;
        }
        bf16x8_t r[4];
#pragma unroll
        for (int i = 0; i < 4; ++i)
            r[i] = *(const bf16x8_t*)&Qb[(size_t)idx[i] * DIM + c * 8];
#pragma unroll
        for (int i = 0; i < 4; ++i)
#pragma unroll
            for (int j = 0; j < 8; ++j)
                acc[j] = fmaf(f[i], bf2f((unsigned short)r[i][j]), acc[j]);
    }
#pragma unroll
    for (int j = 0; j < 8; ++j) {
        acc[j] += __shfl_xor(acc[j], 16, 64);
        acc[j] += __shfl_xor(acc[j], 32, 64);
    }
    if (g == 0) {
        float w = inv_deg[node];
        float4 p0 = *(const float4*)&P[(size_t)node * DIM + c * 8];
        float4 p1 = *(const float4*)&P[(size_t)node * DIM + c * 8 + 4];
        *(float4*)&fout[(size_t)node * DIM + c * 8] =
            make_float4(p0.x + acc[0] * w, p0.y + acc[1] * w, p0.z + acc[2] * w, p0.w + acc[3] * w);
        *(float4*)&fout[(size_t)node * DIM + c * 8 + 4] =
            make_float4(p1.x + acc[4] * w, p1.y + acc[5] * w, p1.z + acc[6] * w, p1.w + acc[7] * w);
    }
}

// ---------------- launch ----------------

extern "C" void kernel_launch(void* const* d_in, const int* in_sizes, int n_in,
                              void* d_out, int out_size, void* d_ws, size_t ws_size,
                              hipStream_t stream) {
    const float* x      = (const float*)d_in[0];
    const int*   src    = (const int*)d_in[1];
    const int*   dst    = (const int*)d_in[2];
    const float* w_self = (const float*)d_in[3];
    const float* w_neigh= (const float*)d_in[4];
    const float* b      = (const float*)d_in[5];
    float* out = (float*)d_out;

    // workspace carve (~90 MB): P/Q ping-pong across fused layers
    char* ws = (char*)d_ws;
    unsigned short* h_hi = (unsigned short*)ws; ws += (size_t)N_NODES * DIM * 2;
    unsigned short* h_lo = (unsigned short*)ws; ws += (size_t)N_NODES * DIM * 2;
    float* Pbuf[2];
    unsigned short* Qbuf[2];
    Pbuf[0] = (float*)ws;          ws += (size_t)N_NODES * DIM * 4;
    Pbuf[1] = (float*)ws;          ws += (size_t)N_NODES * DIM * 4;
    Qbuf[0] = (unsigned short*)ws; ws += (size_t)N_NODES * DIM * 2;
    Qbuf[1] = (unsigned short*)ws; ws += (size_t)N_NODES * DIM * 2;
    unsigned short* wt_hi= (unsigned short*)ws; ws += (size_t)N_LAYERS * 2 * DIM * DIM * 2;
    unsigned short* wt_lo= (unsigned short*)ws; ws += (size_t)N_LAYERS * 2 * DIM * DIM * 2;
    int*   deg     = (int*)ws;  ws += (size_t)N_NODES * 4;
    int*   offsets = (int*)ws;  ws += (size_t)(N_NODES + 4) * 4;
    int*   cursor  = (int*)ws;  ws += (size_t)N_NODES * 4;
    int*   csr_src = (int*)ws;  ws += (size_t)N_EDGES * 4;
    float* inv_deg = (float*)ws; ws += (size_t)N_NODES * 4;
    int*   bsum    = (int*)ws;  ws += 256 * 4;
    int*   boff    = (int*)ws;

    const int NB = (N_NODES + 255) / 256;  // 157

    hipMemsetAsync(deg, 0, (size_t)(N_NODES + (N_NODES + 4) + N_NODES) * 4, stream);

    hist_kernel<<<(N_EDGES + 255) / 256, 256, 0, stream>>>(dst, deg);
    scan1_kernel<<<NB, 256, 0, stream>>>(deg, offsets, inv_deg, bsum);
    scan2_kernel<<<1, 256, 0, stream>>>(bsum, boff);
    scan3_kernel<<<NB, 256, 0, stream>>>(offsets, deg, boff);
    scatter_kernel<<<(N_EDGES + 255) / 256, 256, 0, stream>>>(src, dst, offsets, cursor, csr_src);
    wprep_kernel<<<(N_LAYERS * 2 * DIM * DIM + 255) / 256, 256, 0, stream>>>(w_self, w_neigh, wt_hi, wt_lo);
    split_kernel<<<(N_NODES * DIM / 4 + 255) / 256, 256, 0, stream>>>(x, h_hi, h_lo);

    const int GEMM_BLOCKS = N_NODES / 64;         // 625 (exact)
    const int AGG_BLOCKS = (N_NODES * 64) / 256;  // 10000 (exact)

    // layer 0 GEMM from x
    gemm_pq_kernel<<<GEMM_BLOCKS, 256, 0, stream>>>(
        h_hi, h_lo, wt_hi, wt_lo, b, Pbuf[0], Qbuf[0]);

    // layer boundaries 0->1 and 1->2 (fused agg + next-layer GEMM)
    for (int l = 0; l < N_LAYERS - 1; ++l) {
        int cur = l & 1, nxt = cur ^ 1;
        fused_layer_kernel<<<GEMM_BLOCKS, 256, 0, stream>>>(
            Qbuf[cur], Pbuf[cur], offsets, csr_src, inv_deg,
            wt_hi + (size_t)(l + 1) * 2 * DIM * DIM, wt_lo + (size_t)(l + 1) * 2 * DIM * DIM,
            b + (size_t)(l + 1) * DIM,
            Pbuf[nxt], Qbuf[nxt]);
    }

    // final: out = P2 + agg(Q2)
    final_agg_kernel<<<AGG_BLOCKS, 256, 0, stream>>>(
        Qbuf[(N_LAYERS - 1) & 1], Pbuf[(N_LAYERS - 1) & 1],
        offsets, csr_src, inv_deg, out);
}